// Round 1
// baseline (491.217 us; speedup 1.0000x reference)
//
#include <hip/hip_runtime.h>

#define Bq 8
#define Nq 4096
#define Cq 128
#define Dq 16

// ---------------------------------------------------------------------------
// K1: F/G/H projections.  One wave per row of x; lanes 0..47 each compute one
// (which, d) output via 128-FMA dot against the LDS-staged x row.
// ---------------------------------------------------------------------------
__global__ __launch_bounds__(256) void k_proj(const float* __restrict__ x,
        const float* __restrict__ wf, const float* __restrict__ wg,
        const float* __restrict__ wh, float* __restrict__ F,
        float* __restrict__ G, float* __restrict__ Hh) {
    __shared__ float xrow[4][Cq];
    const int wave = threadIdx.x >> 6;
    const int lane = threadIdx.x & 63;
    const long row = (long)blockIdx.x * 4 + wave;      // in [0, B*N)
    const float* xr = x + row * Cq;
    xrow[wave][lane]      = xr[lane];
    xrow[wave][lane + 64] = xr[lane + 64];
    __syncthreads();
    if (lane < 48) {
        const int which = lane >> 4;                   // 0=f 1=g 2=h
        const int d = lane & 15;
        const float* W = (which == 0) ? wf : ((which == 1) ? wg : wh);
        float s = 0.f;
        #pragma unroll 8
        for (int c = 0; c < Cq; ++c)
            s = fmaf(xrow[wave][c], W[c * Dq + d], s);
        float* O = (which == 0) ? F : ((which == 1) ? G : Hh);
        O[row * Dq + d] = s;
    }
}

// ---------------------------------------------------------------------------
// K2: per-column softmax stats.  Block = 64 columns x 4 n-partitions (one wave
// per partition).  F staged through LDS in 128-row chunks; online max/sum per
// thread, 4-way combine at the end.  Writes M[m] and 1/Z[m].
// ---------------------------------------------------------------------------
__global__ __launch_bounds__(256) void k_colstats(const float* __restrict__ F,
        const float* __restrict__ G, float* __restrict__ Mv,
        float* __restrict__ RZ) {
    const int b    = blockIdx.x >> 6;
    const int tile = blockIdx.x & 63;
    const int lane = threadIdx.x & 63;
    const int tp   = threadIdx.x >> 6;                 // wave id = n-partition
    const int m    = tile * 64 + lane;

    float gv[Dq];
    {
        const float* gb = G + ((long)b * Nq + m) * Dq;
        #pragma unroll
        for (int k = 0; k < Dq; ++k) gv[k] = gb[k];
    }

    __shared__ float fls[128][Dq];                     // 8 KB
    const float* Fb = F + (long)b * Nq * Dq;

    float mt = -1e30f, zt = 0.f;
    for (int n0 = 0; n0 < Nq; n0 += 128) {
        __syncthreads();
        const float4* src = (const float4*)(Fb + (long)n0 * Dq);
        float4* dst = (float4*)&fls[0][0];
        dst[threadIdx.x]       = src[threadIdx.x];
        dst[threadIdx.x + 256] = src[threadIdx.x + 256];
        __syncthreads();
        #pragma unroll 4
        for (int i = 0; i < 32; ++i) {
            const int nn = i * 4 + tp;                 // uniform per wave
            float s = 0.f;
            #pragma unroll
            for (int k = 0; k < Dq; ++k) s = fmaf(fls[nn][k], gv[k], s);
            if (s > mt) { zt *= __expf(mt - s); mt = s; }
            zt += __expf(s - mt);
        }
    }

    __shared__ float mred[4][64];
    __shared__ float zred[4][64];
    mred[tp][lane] = mt;
    zred[tp][lane] = zt;
    __syncthreads();
    if (tp == 0) {
        float mf = mred[0][lane];
        #pragma unroll
        for (int i = 1; i < 4; ++i) mf = fmaxf(mf, mred[i][lane]);
        float z = 0.f;
        #pragma unroll
        for (int i = 0; i < 4; ++i) z += zred[i][lane] * __expf(mred[i][lane] - mf);
        Mv[(long)b * Nq + m] = mf;
        RZ[(long)b * Nq + m] = 1.0f / z;               // z >= 1 always
    }
}

// ---------------------------------------------------------------------------
// K3: y[n,d] = sum_m exp(f[n].g[m] - M[m]) * (Hh[m,d] / Z[m]).
// Block = 64 n-rows x 4 m-partitions.  G / (Hh*rz) / M staged in 64-row LDS
// chunks; per-thread acc[16] in registers; 4-way LDS reduce at the end.
// ---------------------------------------------------------------------------
__global__ __launch_bounds__(256) void k_pv(const float* __restrict__ F,
        const float* __restrict__ G, const float* __restrict__ Hh,
        const float* __restrict__ Mv, const float* __restrict__ RZ,
        float* __restrict__ Y) {
    const int b    = blockIdx.x >> 6;
    const int tile = blockIdx.x & 63;
    const int lane = threadIdx.x & 63;
    const int tp   = threadIdx.x >> 6;                 // wave id = m-partition
    const int n    = tile * 64 + lane;

    float fv[Dq];
    {
        const float* fr = F + ((long)b * Nq + n) * Dq;
        #pragma unroll
        for (int k = 0; k < Dq; ++k) fv[k] = fr[k];
    }
    float acc[Dq];
    #pragma unroll
    for (int k = 0; k < Dq; ++k) acc[k] = 0.f;

    __shared__ float gls[64][Dq];                      // 4 KB
    __shared__ float hls[64][Dq];                      // 4 KB
    __shared__ float mls[64];

    const float* Gb = G  + (long)b * Nq * Dq;
    const float* Hb = Hh + (long)b * Nq * Dq;
    const float* Mb = Mv + (long)b * Nq;
    const float* Rb = RZ + (long)b * Nq;

    for (int m0 = 0; m0 < Nq; m0 += 64) {
        __syncthreads();
        // stage G chunk: 1024 floats = 256 x float4
        ((float4*)&gls[0][0])[threadIdx.x] =
            ((const float4*)(Gb + (long)m0 * Dq))[threadIdx.x];
        // stage Hh chunk scaled by 1/Z
        {
            const int j = threadIdx.x >> 2;            // row in chunk
            const int q = threadIdx.x & 3;             // float4 slot
            const float rz = Rb[m0 + j];
            float4 h4 = ((const float4*)(Hb + (long)(m0 + j) * Dq))[q];
            h4.x *= rz; h4.y *= rz; h4.z *= rz; h4.w *= rz;
            ((float4*)&hls[j][0])[q] = h4;
        }
        if (threadIdx.x < 64) mls[threadIdx.x] = Mb[m0 + threadIdx.x];
        __syncthreads();
        #pragma unroll 2
        for (int i = 0; i < 16; ++i) {
            const int mm = i * 4 + tp;                 // uniform per wave
            float s = 0.f;
            #pragma unroll
            for (int k = 0; k < Dq; ++k) s = fmaf(gls[mm][k], fv[k], s);
            const float p = __expf(s - mls[mm]);
            #pragma unroll
            for (int k = 0; k < Dq; ++k) acc[k] = fmaf(p, hls[mm][k], acc[k]);
        }
    }

    __shared__ float red[4][64][Dq + 1];               // +1 pad: avoid 32-way conflict
    #pragma unroll
    for (int k = 0; k < Dq; ++k) red[tp][lane][k] = acc[k];
    __syncthreads();
    if (tp == 0) {
        #pragma unroll
        for (int k = 0; k < Dq; ++k)
            acc[k] = red[0][lane][k] + red[1][lane][k]
                   + red[2][lane][k] + red[3][lane][k];
        float* yo = Y + ((long)b * Nq + n) * Dq;
        #pragma unroll
        for (int q = 0; q < 4; ++q)
            ((float4*)yo)[q] = make_float4(acc[q * 4], acc[q * 4 + 1],
                                           acc[q * 4 + 2], acc[q * 4 + 3]);
    }
}

// ---------------------------------------------------------------------------
// K4: out = gamma * (Y @ w_v) + x.  Block covers 2 rows x 128 channels.
// ---------------------------------------------------------------------------
__global__ __launch_bounds__(256) void k_out(const float* __restrict__ Y,
        const float* __restrict__ wv, const float* __restrict__ x,
        const float* __restrict__ gamma, float* __restrict__ out) {
    __shared__ float yl[2][Dq];
    const long row0 = (long)blockIdx.x * 2;
    if (threadIdx.x < 32)
        yl[threadIdx.x >> 4][threadIdx.x & 15] =
            Y[(row0 + (threadIdx.x >> 4)) * Dq + (threadIdx.x & 15)];
    __syncthreads();
    const long idx = (long)blockIdx.x * 256 + threadIdx.x;
    const int  c = (int)(idx & 127);
    const int  r = threadIdx.x >> 7;
    float s = 0.f;
    #pragma unroll
    for (int d = 0; d < Dq; ++d)
        s = fmaf(yl[r][d], wv[d * Cq + c], s);
    out[idx] = fmaf(gamma[0], s, x[idx]);
}

// ---------------------------------------------------------------------------
extern "C" void kernel_launch(void* const* d_in, const int* in_sizes, int n_in,
                              void* d_out, int out_size, void* d_ws, size_t ws_size,
                              hipStream_t stream) {
    const float* x     = (const float*)d_in[0];
    const float* wf    = (const float*)d_in[1];
    const float* wg    = (const float*)d_in[2];
    const float* wh    = (const float*)d_in[3];
    const float* wv    = (const float*)d_in[4];
    const float* gamma = (const float*)d_in[5];
    float* out = (float*)d_out;

    // workspace layout (floats): F,G,H [B][N][D]; M,RZ [B][N]; Y [B][N][D]
    float* ws = (float*)d_ws;
    const long nd = (long)Bq * Nq * Dq;                // 524288
    float* F  = ws;
    float* G  = F + nd;
    float* Hh = G + nd;
    float* Mv = Hh + nd;
    float* RZ = Mv + (long)Bq * Nq;
    float* Y  = RZ + (long)Bq * Nq;

    k_proj    <<<(Bq * Nq) / 4,        256, 0, stream>>>(x, wf, wg, wh, F, G, Hh);
    k_colstats<<<Bq * (Nq / 64),       256, 0, stream>>>(F, G, Mv, RZ);
    k_pv      <<<Bq * (Nq / 64),       256, 0, stream>>>(F, G, Hh, Mv, RZ, Y);
    k_out     <<<(Bq * Nq) / 2,        256, 0, stream>>>(Y, wv, x, gamma, out);
}

// Round 5
// 102.631 us; speedup vs baseline: 4.7862x; 4.7862x over previous
//
#include <hip/hip_runtime.h>

typedef _Float16 f16;
typedef _Float16 f16x4 __attribute__((ext_vector_type(4)));
typedef _Float16 n16x2 __attribute__((ext_vector_type(2)));
typedef float    f32x4 __attribute__((ext_vector_type(4)));

#define LOG2E 1.44269504088896340736f
#define OFF25 36.0673760222824936f   /* 25 * log2(e) */

__device__ __forceinline__ f32x4 MFMA(f16x4 a, f16x4 b, f32x4 c) {
#if defined(__HIP_DEVICE_COMPILE__)
    return __builtin_amdgcn_mfma_f32_16x16x16f16(a, b, c, 0, 0, 0);
#else
    return c;   // host parse stub — never executed
#endif
}

__device__ __forceinline__ float fexp2(float x) {
#if defined(__HIP_DEVICE_COMPILE__)
    return __builtin_amdgcn_exp2f(x);
#else
    return exp2f(x);
#endif
}

__device__ __forceinline__ f16x4 pk4(float a, float b, float c, float d) {
#if defined(__HIP_DEVICE_COMPILE__)
    n16x2 lo = __builtin_bit_cast(n16x2, __builtin_amdgcn_cvt_pkrtz(a, b));
    n16x2 hi = __builtin_bit_cast(n16x2, __builtin_amdgcn_cvt_pkrtz(c, d));
    f16x4 r; r[0] = lo[0]; r[1] = lo[1]; r[2] = hi[0]; r[3] = hi[1];
    return r;
#else
    f16x4 r; r[0] = (f16)a; r[1] = (f16)b; r[2] = (f16)c; r[3] = (f16)d;
    return r;
#endif
}

// ---------------------------------------------------------------------------
// K1: projections via MFMA.  Wave = 16 rows; K=128 in 8 k-steps; 3 accs
// (F,G -> f16 workspace; H -> f32 workspace).  x cast to f16 in-flight.
// ---------------------------------------------------------------------------
__global__ __launch_bounds__(256) void k_proj(const float* __restrict__ x,
        const float* __restrict__ wf, const float* __restrict__ wg,
        const float* __restrict__ wh, f16* __restrict__ F,
        f16* __restrict__ G, float* __restrict__ Hh) {
    const int lane = threadIdx.x & 63;
    const int wid  = threadIdx.x >> 6;
    const int g16  = lane >> 4;          // 0..3
    const int c16  = lane & 15;          // 0..15
    const long r0  = ((long)blockIdx.x * 4 + wid) * 16;

    // B-fragments: bw[w][kk][j] = W[kk*16 + 4*g16 + j][c16]
    f16x4 bw[3][8];
    const float* Ws[3] = { wf, wg, wh };
    #pragma unroll
    for (int w = 0; w < 3; ++w)
        #pragma unroll
        for (int kk = 0; kk < 8; ++kk) {
            const int kb = kk * 16 + g16 * 4;
            bw[w][kk] = pk4(Ws[w][(kb + 0) * 16 + c16], Ws[w][(kb + 1) * 16 + c16],
                            Ws[w][(kb + 2) * 16 + c16], Ws[w][(kb + 3) * 16 + c16]);
        }

    f32x4 af = {0,0,0,0}, ag = {0,0,0,0}, ah = {0,0,0,0};
    const float* xr = x + (r0 + c16) * 128;
    #pragma unroll
    for (int kk = 0; kk < 8; ++kk) {
        float4 xa = *(const float4*)(xr + kk * 16 + g16 * 4);
        f16x4 a = pk4(xa.x, xa.y, xa.z, xa.w);
        af = MFMA(a, bw[0][kk], af);
        ag = MFMA(a, bw[1][kk], ag);
        ah = MFMA(a, bw[2][kk], ah);
    }
    #pragma unroll
    for (int i = 0; i < 4; ++i) {
        const long row = r0 + g16 * 4 + i;
        F[row * 16 + c16]  = (f16)af[i];
        G[row * 16 + c16]  = (f16)ag[i];
        Hh[row * 16 + c16] = ah[i];
    }
}

// ---------------------------------------------------------------------------
// K2: column stats.  Wave owns a 16-m strip; iterates a 1024-n quarter in
// 16-n MFMA tiles: S^T = mfma(A=G, B=F).  Per (lane,reg): running
// sum of exp2(s*log2e - 36.07) and running max (combine = plain add/max).
// ---------------------------------------------------------------------------
__global__ __launch_bounds__(256) void k_cs(const f16* __restrict__ F,
        const f16* __restrict__ G, float* __restrict__ QMp,
        float* __restrict__ Zp) {
    const int lane = threadIdx.x & 63;
    const int tp   = threadIdx.x >> 6;
    const int b    = blockIdx.x >> 8;
    const int rem  = blockIdx.x & 255;
    const int mblk = rem >> 2;
    const int np   = rem & 3;
    const int g16  = lane >> 4, c16 = lane & 15;
    const int m0   = mblk * 64 + tp * 16;
    const long bb  = (long)b * 4096;

    const f16x4 ga = *(const f16x4*)(G + (bb + m0 + c16) * 16 + g16 * 4);
    const f16* Fb  = F + (bb + np * 1024) * 16;

    float qm[4] = { -1e30f, -1e30f, -1e30f, -1e30f };
    float zs[4] = { 0.f, 0.f, 0.f, 0.f };
    for (int t = 0; t < 64; ++t) {
        f16x4 fb = *(const f16x4*)(Fb + (t * 16 + c16) * 16 + g16 * 4);
        f32x4 zero = {0,0,0,0};
        f32x4 s = MFMA(ga, fb, zero);
        #pragma unroll
        for (int i = 0; i < 4; ++i) {
            const float q = fmaf(s[i], LOG2E, -OFF25);
            zs[i] += fexp2(q);
            qm[i] = fmaxf(qm[i], q);
        }
    }
    #pragma unroll
    for (int d = 8; d >= 1; d >>= 1)
        #pragma unroll
        for (int i = 0; i < 4; ++i) {
            qm[i] = fmaxf(qm[i], __shfl_xor(qm[i], d));
            zs[i] += __shfl_xor(zs[i], d);
        }
    if (c16 == 0) {
        const long base = (long)np * 32768 + bb + m0 + g16 * 4;
        #pragma unroll
        for (int i = 0; i < 4; ++i) {
            QMp[base + i] = qm[i];
            Zp[base + i]  = zs[i];
        }
    }
}

// ---------------------------------------------------------------------------
// K3: combine 4 n-partials -> nM2[m] = -(qmax + 36.07)  (exp2-domain -max),
//                             RZ[m]  = exp2(qmax) / Z25[m]   (fold into H).
// ---------------------------------------------------------------------------
__global__ __launch_bounds__(256) void k_fin(const float* __restrict__ QMp,
        const float* __restrict__ Zp, float* __restrict__ nM2,
        float* __restrict__ RZ) {
    const int i = blockIdx.x * 256 + threadIdx.x;   // 0..32767
    float qm = QMp[i], zt = Zp[i];
    #pragma unroll
    for (int p = 1; p < 4; ++p) {
        qm = fmaxf(qm, QMp[p * 32768 + i]);
        zt += Zp[p * 32768 + i];
    }
    nM2[i] = -qm - OFF25;
    RZ[i]  = fexp2(qm) / zt;
}

// ---------------------------------------------------------------------------
// K4: PV + fused output projection.  Block = 16 n-rows; 4 waves split the
// m-range 4 ways.  Per 16-m tile: S^T mfma -> exp -> (zero-shuffle) -> PV
// mfma with A = (H*rz)^T.  Cross-wave LDS sum of Y^T, then Y^T regs feed the
// (Y @ gamma*w_v) mfma directly; +x residual; store f32.
// ---------------------------------------------------------------------------
__global__ __launch_bounds__(256) void k_pv(const f16* __restrict__ F,
        const f16* __restrict__ G, const float* __restrict__ Hh,
        const float* __restrict__ nM2, const float* __restrict__ RZ,
        const float* __restrict__ wv, const float* __restrict__ xin,
        const float* __restrict__ gamma, float* __restrict__ out) {
    const int lane = threadIdx.x & 63;
    const int tp   = threadIdx.x >> 6;
    const int b    = blockIdx.x >> 8;
    const int n0   = (blockIdx.x & 255) * 16;
    const int g16  = lane >> 4, c16 = lane & 15;
    const long bb  = (long)b * 4096;

    // fixed B-fragment: F rows n0..n0+15
    const f16x4 fb = *(const f16x4*)(F + (bb + n0 + c16) * 16 + g16 * 4);

    // w_v fragments (gamma folded), col tiles 2*tp and 2*tp+1
    const float gm = gamma[0];
    f16x4 wvf[2];
    #pragma unroll
    for (int t = 0; t < 2; ++t) {
        const int c0 = (tp * 2 + t) * 16;
        wvf[t] = pk4(wv[(g16 * 4 + 0) * 128 + c0 + c16] * gm,
                     wv[(g16 * 4 + 1) * 128 + c0 + c16] * gm,
                     wv[(g16 * 4 + 2) * 128 + c0 + c16] * gm,
                     wv[(g16 * 4 + 3) * 128 + c0 + c16] * gm);
    }

    f32x4 yT = {0,0,0,0};
    const int mbase = tp * 1024;
    for (int t = 0; t < 64; ++t) {
        const int m0 = mbase + t * 16;
        f16x4 ga = *(const f16x4*)(G + (bb + m0 + c16) * 16 + g16 * 4);
        f32x4 zero = {0,0,0,0};
        f32x4 s = MFMA(ga, fb, zero);
        f32x4 nm = *(const f32x4*)(nM2 + bb + m0 + g16 * 4);
        f32x4 rz = *(const f32x4*)(RZ  + bb + m0 + g16 * 4);
        // P^T tile: B-frag == S^T C-regs elementwise (zero shuffle)
        f16x4 pb = pk4(fexp2(fmaf(s[0], LOG2E, nm[0])),
                       fexp2(fmaf(s[1], LOG2E, nm[1])),
                       fexp2(fmaf(s[2], LOG2E, nm[2])),
                       fexp2(fmaf(s[3], LOG2E, nm[3])));
        // A-frag: H'^T[d=c16][m0+4*g16+j]
        const float* hp = Hh + (bb + m0 + g16 * 4) * 16 + c16;
        f16x4 ha = pk4(hp[0]  * rz[0], hp[16] * rz[1],
                       hp[32] * rz[2], hp[48] * rz[3]);
        yT = MFMA(ha, pb, yT);
    }

    // cross-wave reduce of Y^T partials (stride 5 floats: conflict-free)
    __shared__ float red[4][64][5];
    #pragma unroll
    for (int i = 0; i < 4; ++i) red[tp][lane][i] = yT[i];
    __syncthreads();
    f32x4 ys;
    #pragma unroll
    for (int i = 0; i < 4; ++i)
        ys[i] = red[0][lane][i] + red[1][lane][i]
              + red[2][lane][i] + red[3][lane][i];
    const f16x4 ya = pk4(ys[0], ys[1], ys[2], ys[3]);   // A-frag of Y (zero shuffle)

    #pragma unroll
    for (int t = 0; t < 2; ++t) {
        const int c0 = (tp * 2 + t) * 16;
        f32x4 zero = {0,0,0,0};
        f32x4 o = MFMA(ya, wvf[t], zero);
        #pragma unroll
        for (int i = 0; i < 4; ++i) {
            const long idx = (bb + n0 + g16 * 4 + i) * 128 + c0 + c16;
            out[idx] = o[i] + xin[idx];
        }
    }
}

// ---------------------------------------------------------------------------
extern "C" void kernel_launch(void* const* d_in, const int* in_sizes, int n_in,
                              void* d_out, int out_size, void* d_ws, size_t ws_size,
                              hipStream_t stream) {
    const float* x     = (const float*)d_in[0];
    const float* wf    = (const float*)d_in[1];
    const float* wg    = (const float*)d_in[2];
    const float* wh    = (const float*)d_in[3];
    const float* wv    = (const float*)d_in[4];
    const float* gamma = (const float*)d_in[5];
    float* out = (float*)d_out;

    // workspace carve-up (all 256B-aligned by construction)
    char* p = (char*)d_ws;
    const long BN = 8L * 4096;                 // 32768 rows
    f16*   F   = (f16*)p;            p += BN * 16 * sizeof(f16);    // 1 MB
    f16*   G   = (f16*)p;            p += BN * 16 * sizeof(f16);    // 1 MB
    float* Hh  = (float*)p;          p += BN * 16 * sizeof(float);  // 2 MB
    float* QMp = (float*)p;          p += 4 * BN * sizeof(float);   // 512 KB
    float* Zp  = (float*)p;          p += 4 * BN * sizeof(float);   // 512 KB
    float* nM2 = (float*)p;          p += BN * sizeof(float);       // 128 KB
    float* RZ  = (float*)p;          p += BN * sizeof(float);       // 128 KB

    k_proj<<<512,  256, 0, stream>>>(x, wf, wg, wh, F, G, Hh);
    k_cs  <<<2048, 256, 0, stream>>>(F, G, QMp, Zp);
    k_fin <<<128,  256, 0, stream>>>(QMp, Zp, nM2, RZ);
    k_pv  <<<2048, 256, 0, stream>>>(F, G, Hh, nM2, RZ, wv, x, gamma, out);
}

// Round 6
// 85.717 us; speedup vs baseline: 5.7307x; 1.1973x over previous
//
#include <hip/hip_runtime.h>

typedef _Float16 f16;
typedef _Float16 f16x4 __attribute__((ext_vector_type(4)));
typedef _Float16 n16x2 __attribute__((ext_vector_type(2)));
typedef float    f32x4 __attribute__((ext_vector_type(4)));

#define LOG2E 1.44269504088896340736f
#define OFF25 36.0673760222824936f   /* 25 * log2(e) */

__device__ __forceinline__ f32x4 MFMA(f16x4 a, f16x4 b, f32x4 c) {
#if defined(__HIP_DEVICE_COMPILE__)
    return __builtin_amdgcn_mfma_f32_16x16x16f16(a, b, c, 0, 0, 0);
#else
    return c;   // host parse stub — never executed
#endif
}

__device__ __forceinline__ float fexp2(float x) {
#if defined(__HIP_DEVICE_COMPILE__)
    return __builtin_amdgcn_exp2f(x);
#else
    return exp2f(x);
#endif
}

__device__ __forceinline__ f16x4 pk4(float a, float b, float c, float d) {
#if defined(__HIP_DEVICE_COMPILE__)
    n16x2 lo = __builtin_bit_cast(n16x2, __builtin_amdgcn_cvt_pkrtz(a, b));
    n16x2 hi = __builtin_bit_cast(n16x2, __builtin_amdgcn_cvt_pkrtz(c, d));
    f16x4 r; r[0] = lo[0]; r[1] = lo[1]; r[2] = hi[0]; r[3] = hi[1];
    return r;
#else
    f16x4 r; r[0] = (f16)a; r[1] = (f16)b; r[2] = (f16)c; r[3] = (f16)d;
    return r;
#endif
}

// ---------------------------------------------------------------------------
// K1: projections.  Wave = 16 rows.  F,G row-major f16; H written TRANSPOSED
// f32: Ht[d][B*N] (d-major) so the V-prep and PV passes are vector loads.
// ---------------------------------------------------------------------------
__global__ __launch_bounds__(256) void k_proj(const float* __restrict__ x,
        const float* __restrict__ wf, const float* __restrict__ wg,
        const float* __restrict__ wh, f16* __restrict__ F,
        f16* __restrict__ G, float* __restrict__ Ht) {
    const int lane = threadIdx.x & 63;
    const int wid  = threadIdx.x >> 6;
    const int g16  = lane >> 4;          // 0..3
    const int c16  = lane & 15;          // 0..15
    const long r0  = ((long)blockIdx.x * 4 + wid) * 16;

    f16x4 bw[3][8];
    const float* Ws[3] = { wf, wg, wh };
    #pragma unroll
    for (int w = 0; w < 3; ++w)
        #pragma unroll
        for (int kk = 0; kk < 8; ++kk) {
            const int kb = kk * 16 + g16 * 4;
            bw[w][kk] = pk4(Ws[w][(kb + 0) * 16 + c16], Ws[w][(kb + 1) * 16 + c16],
                            Ws[w][(kb + 2) * 16 + c16], Ws[w][(kb + 3) * 16 + c16]);
        }

    f32x4 af = {0,0,0,0}, ag = {0,0,0,0}, ah = {0,0,0,0};
    const float* xr = x + (r0 + c16) * 128;
    #pragma unroll
    for (int kk = 0; kk < 8; ++kk) {
        float4 xa = *(const float4*)(xr + kk * 16 + g16 * 4);
        f16x4 a = pk4(xa.x, xa.y, xa.z, xa.w);
        af = MFMA(a, bw[0][kk], af);
        ag = MFMA(a, bw[1][kk], ag);
        ah = MFMA(a, bw[2][kk], ah);
    }
    #pragma unroll
    for (int i = 0; i < 4; ++i) {
        const long row = r0 + g16 * 4 + i;
        F[row * 16 + c16] = (f16)af[i];
        G[row * 16 + c16] = (f16)ag[i];
    }
    // ah[i] = H[row = r0+4*g16+i][d = c16] -> Ht[c16][r0+4*g16 .. +3]
    float4 hv = make_float4(ah[0], ah[1], ah[2], ah[3]);
    *(float4*)(Ht + (long)c16 * 32768 + r0 + g16 * 4) = hv;
}

// ---------------------------------------------------------------------------
// K2: column stats, 4-tile ILP.  Block = 64 m (4 tiles, ga[4] per wave);
// 4 waves cover the 4 n-quarters; fixed-offset exp2 partial sums combine by
// plain add across waves -> write final nM2 / RZ directly.
// ---------------------------------------------------------------------------
__global__ __launch_bounds__(256) void k_cs(const f16* __restrict__ F,
        const f16* __restrict__ G, float* __restrict__ nM2,
        float* __restrict__ RZ) {
    const int lane = threadIdx.x & 63;
    const int tp   = threadIdx.x >> 6;
    const int b    = blockIdx.x >> 6;
    const int mb   = (blockIdx.x & 63) * 64;
    const int g16  = lane >> 4, c16 = lane & 15;
    const long bb  = (long)b * 4096;

    f16x4 ga[4];
    #pragma unroll
    for (int j = 0; j < 4; ++j)
        ga[j] = *(const f16x4*)(G + (bb + mb + 16 * j + c16) * 16 + g16 * 4);

    const f16* Fb = F + (bb + tp * 1024) * 16;
    float qm[4][4], zs[4][4];
    #pragma unroll
    for (int j = 0; j < 4; ++j)
        #pragma unroll
        for (int i = 0; i < 4; ++i) { qm[j][i] = -1e30f; zs[j][i] = 0.f; }

    for (int t = 0; t < 64; ++t) {
        f16x4 fbv = *(const f16x4*)(Fb + (t * 16 + c16) * 16 + g16 * 4);
        #pragma unroll
        for (int j = 0; j < 4; ++j) {
            f32x4 zero = {0,0,0,0};
            f32x4 s = MFMA(ga[j], fbv, zero);
            #pragma unroll
            for (int i = 0; i < 4; ++i) {
                const float q = fmaf(s[i], LOG2E, -OFF25);
                zs[j][i] += fexp2(q);
                qm[j][i] = fmaxf(qm[j][i], q);
            }
        }
    }
    #pragma unroll
    for (int d = 8; d >= 1; d >>= 1)
        #pragma unroll
        for (int j = 0; j < 4; ++j)
            #pragma unroll
            for (int i = 0; i < 4; ++i) {
                qm[j][i] = fmaxf(qm[j][i], __shfl_xor(qm[j][i], d));
                zs[j][i] += __shfl_xor(zs[j][i], d);
            }

    __shared__ float lq[4][64], lz[4][64];
    if (c16 == 0) {
        #pragma unroll
        for (int j = 0; j < 4; ++j)
            #pragma unroll
            for (int i = 0; i < 4; ++i) {
                const int ml = 16 * j + 4 * g16 + i;
                lq[tp][ml] = qm[j][i];
                lz[tp][ml] = zs[j][i];
            }
    }
    __syncthreads();
    if (threadIdx.x < 64) {
        const int ml = threadIdx.x;
        float q = fmaxf(fmaxf(lq[0][ml], lq[1][ml]), fmaxf(lq[2][ml], lq[3][ml]));
        float z = lz[0][ml] + lz[1][ml] + lz[2][ml] + lz[3][ml];
        nM2[bb + mb + ml] = -q - OFF25;
        RZ[bb + mb + ml]  = fexp2(q) / z;
    }
}

// ---------------------------------------------------------------------------
// K3: Hs[d][m] = f16( Ht[d][m] * RZ[m] ) — fully coalesced scale+cast.
// ---------------------------------------------------------------------------
__global__ __launch_bounds__(256) void k_hs(const float* __restrict__ Ht,
        const float* __restrict__ RZ, f16* __restrict__ Hs) {
    const long cid = (long)blockIdx.x * 256 + threadIdx.x;  // 0..131071
    const int  d   = (int)(cid >> 13);
    const long m4  = (cid & 8191) * 4;
    f32x4 h = *(const f32x4*)(Ht + (long)d * 32768 + m4);
    f32x4 r = *(const f32x4*)(RZ + m4);
    *(f16x4*)(Hs + (long)d * 32768 + m4) = pk4(h[0]*r[0], h[1]*r[1], h[2]*r[2], h[3]*r[3]);
}

// ---------------------------------------------------------------------------
// K4: PV + fused output projection, 4-tile ILP.  Block = 64 n-rows; wave tp
// owns m-quarter.  Per m-tile: {ga, ha, nm} loads amortized over 4 S-MFMAs +
// 4 independent PV accumulator chains.  LDS reduce; wave tp projects n-tile
// tp to all 128 output channels (+x residual).
// ---------------------------------------------------------------------------
__global__ __launch_bounds__(256) void k_pv(const f16* __restrict__ F,
        const f16* __restrict__ G, const f16* __restrict__ Hs,
        const float* __restrict__ nM2, const float* __restrict__ wv,
        const float* __restrict__ xin, const float* __restrict__ gamma,
        float* __restrict__ out) {
    const int lane = threadIdx.x & 63;
    const int tp   = threadIdx.x >> 6;
    const int b    = blockIdx.x >> 6;
    const int n0   = (blockIdx.x & 63) * 64;
    const int g16  = lane >> 4, c16 = lane & 15;
    const long bb  = (long)b * 4096;

    f16x4 fbv[4];
    #pragma unroll
    for (int j = 0; j < 4; ++j)
        fbv[j] = *(const f16x4*)(F + (bb + n0 + 16 * j + c16) * 16 + g16 * 4);

    const float gm = gamma[0];
    f16x4 wvf[8];
    #pragma unroll
    for (int t = 0; t < 8; ++t)
        wvf[t] = pk4(wv[(g16 * 4 + 0) * 128 + 16 * t + c16] * gm,
                     wv[(g16 * 4 + 1) * 128 + 16 * t + c16] * gm,
                     wv[(g16 * 4 + 2) * 128 + 16 * t + c16] * gm,
                     wv[(g16 * 4 + 3) * 128 + 16 * t + c16] * gm);

    f32x4 yT[4] = {{0,0,0,0},{0,0,0,0},{0,0,0,0},{0,0,0,0}};
    for (int t = 0; t < 64; ++t) {
        const int m0 = tp * 1024 + t * 16;
        f16x4 ga = *(const f16x4*)(G + (bb + m0 + c16) * 16 + g16 * 4);
        f16x4 ha = *(const f16x4*)(Hs + (long)c16 * 32768 + bb + m0 + g16 * 4);
        f32x4 nm = *(const f32x4*)(nM2 + bb + m0 + g16 * 4);
        #pragma unroll
        for (int j = 0; j < 4; ++j) {
            f32x4 zero = {0,0,0,0};
            f32x4 s = MFMA(ga, fbv[j], zero);
            f16x4 pb = pk4(fexp2(fmaf(s[0], LOG2E, nm[0])),
                           fexp2(fmaf(s[1], LOG2E, nm[1])),
                           fexp2(fmaf(s[2], LOG2E, nm[2])),
                           fexp2(fmaf(s[3], LOG2E, nm[3])));
            yT[j] = MFMA(ha, pb, yT[j]);
        }
    }

    // cross-wave reduce of the 4 m-partials for each of the 4 n-tiles
    __shared__ float red[4][4][64][5];        // 20 KB, stride-5: conflict-free
    #pragma unroll
    for (int j = 0; j < 4; ++j)
        #pragma unroll
        for (int i = 0; i < 4; ++i) red[tp][j][lane][i] = yT[j][i];
    __syncthreads();

    f32x4 ys;
    #pragma unroll
    for (int i = 0; i < 4; ++i)
        ys[i] = red[0][tp][lane][i] + red[1][tp][lane][i]
              + red[2][tp][lane][i] + red[3][tp][lane][i];
    const f16x4 ya = pk4(ys[0], ys[1], ys[2], ys[3]);   // A-frag of Y, n-tile tp

    #pragma unroll
    for (int t = 0; t < 8; ++t) {
        f32x4 zero = {0,0,0,0};
        f32x4 o = MFMA(ya, wvf[t], zero);
        #pragma unroll
        for (int i = 0; i < 4; ++i) {
            const long idx = (bb + n0 + 16 * tp + 4 * g16 + i) * 128 + 16 * t + c16;
            out[idx] = o[i] + xin[idx];
        }
    }
}

// ---------------------------------------------------------------------------
extern "C" void kernel_launch(void* const* d_in, const int* in_sizes, int n_in,
                              void* d_out, int out_size, void* d_ws, size_t ws_size,
                              hipStream_t stream) {
    const float* x     = (const float*)d_in[0];
    const float* wf    = (const float*)d_in[1];
    const float* wg    = (const float*)d_in[2];
    const float* wh    = (const float*)d_in[3];
    const float* wv    = (const float*)d_in[4];
    const float* gamma = (const float*)d_in[5];
    float* out = (float*)d_out;

    char* p = (char*)d_ws;
    const long BN = 8L * 4096;                 // 32768 rows
    f16*   F   = (f16*)p;    p += BN * 16 * sizeof(f16);    // 1 MB
    f16*   G   = (f16*)p;    p += BN * 16 * sizeof(f16);    // 1 MB
    float* Ht  = (float*)p;  p += 16 * BN * sizeof(float);  // 2 MB  [d][B*N]
    f16*   Hs  = (f16*)p;    p += 16 * BN * sizeof(f16);    // 1 MB  [d][B*N]
    float* nM2 = (float*)p;  p += BN * sizeof(float);       // 128 KB
    float* RZ  = (float*)p;  p += BN * sizeof(float);       // 128 KB

    k_proj<<<512, 256, 0, stream>>>(x, wf, wg, wh, F, G, Ht);
    k_cs  <<<512, 256, 0, stream>>>(F, G, nM2, RZ);
    k_hs  <<<512, 256, 0, stream>>>(Ht, RZ, Hs);
    k_pv  <<<512, 256, 0, stream>>>(F, G, Hs, nM2, wv, x, gamma, out);
}

// Round 7
// 72.062 us; speedup vs baseline: 6.8166x; 1.1895x over previous
//
#include <hip/hip_runtime.h>

typedef _Float16 f16;
typedef _Float16 f16x4 __attribute__((ext_vector_type(4)));
typedef _Float16 n16x2 __attribute__((ext_vector_type(2)));
typedef float    f32x4 __attribute__((ext_vector_type(4)));

#define LOG2E 1.44269504088896340736f
#define OFF25 36.0673760222824936f   /* 25 * log2(e) */

__device__ __forceinline__ f32x4 MFMA(f16x4 a, f16x4 b, f32x4 c) {
#if defined(__HIP_DEVICE_COMPILE__)
    return __builtin_amdgcn_mfma_f32_16x16x16f16(a, b, c, 0, 0, 0);
#else
    return c;   // host parse stub — never executed
#endif
}

__device__ __forceinline__ float fexp2(float x) {
#if defined(__HIP_DEVICE_COMPILE__)
    return __builtin_amdgcn_exp2f(x);
#else
    return exp2f(x);
#endif
}

__device__ __forceinline__ f16x4 pk4(float a, float b, float c, float d) {
#if defined(__HIP_DEVICE_COMPILE__)
    n16x2 lo = __builtin_bit_cast(n16x2, __builtin_amdgcn_cvt_pkrtz(a, b));
    n16x2 hi = __builtin_bit_cast(n16x2, __builtin_amdgcn_cvt_pkrtz(c, d));
    f16x4 r; r[0] = lo[0]; r[1] = lo[1]; r[2] = hi[0]; r[3] = hi[1];
    return r;
#else
    f16x4 r; r[0] = (f16)a; r[1] = (f16)b; r[2] = (f16)c; r[3] = (f16)d;
    return r;
#endif
}

// ---------------------------------------------------------------------------
// K1: projections.  Wave = 16 rows.  F,G row-major f16; H written TRANSPOSED
// f32: Ht[d][B*N] (d-major) so V-prep and PV are vector loads.
// ---------------------------------------------------------------------------
__global__ __launch_bounds__(256) void k_proj(const float* __restrict__ x,
        const float* __restrict__ wf, const float* __restrict__ wg,
        const float* __restrict__ wh, f16* __restrict__ F,
        f16* __restrict__ G, float* __restrict__ Ht) {
    const int lane = threadIdx.x & 63;
    const int wid  = threadIdx.x >> 6;
    const int g16  = lane >> 4;          // 0..3
    const int c16  = lane & 15;          // 0..15
    const long r0  = ((long)blockIdx.x * 4 + wid) * 16;

    f16x4 bw[3][8];
    const float* Ws[3] = { wf, wg, wh };
    #pragma unroll
    for (int w = 0; w < 3; ++w)
        #pragma unroll
        for (int kk = 0; kk < 8; ++kk) {
            const int kb = kk * 16 + g16 * 4;
            bw[w][kk] = pk4(Ws[w][(kb + 0) * 16 + c16], Ws[w][(kb + 1) * 16 + c16],
                            Ws[w][(kb + 2) * 16 + c16], Ws[w][(kb + 3) * 16 + c16]);
        }

    f32x4 af = {0,0,0,0}, ag = {0,0,0,0}, ah = {0,0,0,0};
    const float* xr = x + (r0 + c16) * 128;
    #pragma unroll
    for (int kk = 0; kk < 8; ++kk) {
        float4 xa = *(const float4*)(xr + kk * 16 + g16 * 4);
        f16x4 a = pk4(xa.x, xa.y, xa.z, xa.w);
        af = MFMA(a, bw[0][kk], af);
        ag = MFMA(a, bw[1][kk], ag);
        ah = MFMA(a, bw[2][kk], ah);
    }
    #pragma unroll
    for (int i = 0; i < 4; ++i) {
        const long row = r0 + g16 * 4 + i;
        F[row * 16 + c16] = (f16)af[i];
        G[row * 16 + c16] = (f16)ag[i];
    }
    float4 hv = make_float4(ah[0], ah[1], ah[2], ah[3]);
    *(float4*)(Ht + (long)c16 * 32768 + r0 + g16 * 4) = hv;
}

// ---------------------------------------------------------------------------
// K2: column stats.  Block = 64 m (ga[4] tiles per wave), 8 waves = 8
// n-eighths (512 n each, 32 iters) with register prefetch of the F fragment.
// 8-way LDS combine -> write nM2 / RZ.
// ---------------------------------------------------------------------------
__global__ __launch_bounds__(512) void k_cs(const f16* __restrict__ F,
        const f16* __restrict__ G, float* __restrict__ nM2,
        float* __restrict__ RZ) {
    const int lane = threadIdx.x & 63;
    const int tp   = threadIdx.x >> 6;               // 0..7 n-partition
    const int b    = blockIdx.x >> 6;
    const int mb   = (blockIdx.x & 63) * 64;
    const int g16  = lane >> 4, c16 = lane & 15;
    const long bb  = (long)b * 4096;

    f16x4 ga[4];
    #pragma unroll
    for (int j = 0; j < 4; ++j)
        ga[j] = *(const f16x4*)(G + (bb + mb + 16 * j + c16) * 16 + g16 * 4);

    const f16* Fb = F + (bb + tp * 512) * 16;
    float qm[4][4], zs[4][4];
    #pragma unroll
    for (int j = 0; j < 4; ++j)
        #pragma unroll
        for (int i = 0; i < 4; ++i) { qm[j][i] = -1e30f; zs[j][i] = 0.f; }

    f16x4 fbv = *(const f16x4*)(Fb + (c16) * 16 + g16 * 4);
    for (int t = 0; t < 32; ++t) {
        // prefetch next n-tile's F fragment (buffers padded: safe over-read)
        f16x4 fbn = *(const f16x4*)(Fb + ((t + 1) * 16 + c16) * 16 + g16 * 4);
        #pragma unroll
        for (int j = 0; j < 4; ++j) {
            f32x4 zero = {0,0,0,0};
            f32x4 s = MFMA(ga[j], fbv, zero);
            #pragma unroll
            for (int i = 0; i < 4; ++i) {
                const float q = fmaf(s[i], LOG2E, -OFF25);
                zs[j][i] += fexp2(q);
                qm[j][i] = fmaxf(qm[j][i], q);
            }
        }
        fbv = fbn;
    }
    #pragma unroll
    for (int d = 8; d >= 1; d >>= 1)
        #pragma unroll
        for (int j = 0; j < 4; ++j)
            #pragma unroll
            for (int i = 0; i < 4; ++i) {
                qm[j][i] = fmaxf(qm[j][i], __shfl_xor(qm[j][i], d));
                zs[j][i] += __shfl_xor(zs[j][i], d);
            }

    __shared__ float lq[8][64], lz[8][64];
    if (c16 == 0) {
        #pragma unroll
        for (int j = 0; j < 4; ++j)
            #pragma unroll
            for (int i = 0; i < 4; ++i) {
                const int ml = 16 * j + 4 * g16 + i;
                lq[tp][ml] = qm[j][i];
                lz[tp][ml] = zs[j][i];
            }
    }
    __syncthreads();
    if (threadIdx.x < 64) {
        const int ml = threadIdx.x;
        float q = lq[0][ml], z = 0.f;
        #pragma unroll
        for (int p = 1; p < 8; ++p) q = fmaxf(q, lq[p][ml]);
        #pragma unroll
        for (int p = 0; p < 8; ++p) z += lz[p][ml];
        nM2[bb + mb + ml] = -q - OFF25;
        RZ[bb + mb + ml]  = fexp2(q) / z;
    }
}

// ---------------------------------------------------------------------------
// K3: Hs[d][m] = f16( Ht[d][m] * RZ[m] ) — fully coalesced scale+cast.
// ---------------------------------------------------------------------------
__global__ __launch_bounds__(256) void k_hs(const float* __restrict__ Ht,
        const float* __restrict__ RZ, f16* __restrict__ Hs) {
    const long cid = (long)blockIdx.x * 256 + threadIdx.x;  // 0..131071
    const int  d   = (int)(cid >> 13);
    const long m4  = (cid & 8191) * 4;
    f32x4 h = *(const f32x4*)(Ht + (long)d * 32768 + m4);
    f32x4 r = *(const f32x4*)(RZ + m4);
    *(f16x4*)(Hs + (long)d * 32768 + m4) = pk4(h[0]*r[0], h[1]*r[1], h[2]*r[2], h[3]*r[3]);
}

// ---------------------------------------------------------------------------
// K4: PV + fused output projection.  Block = 64 n-rows (fbv[4] tiles), 8
// waves = 8 m-eighths (512 m, 32 iters) with register prefetch of
// {ga, ha, nm}.  8-partial LDS reduce; epilogue split across all 8 waves.
// ---------------------------------------------------------------------------
__global__ __launch_bounds__(512) void k_pv(const f16* __restrict__ F,
        const f16* __restrict__ G, const f16* __restrict__ Hs,
        const float* __restrict__ nM2, const float* __restrict__ wv,
        const float* __restrict__ xin, const float* __restrict__ gamma,
        float* __restrict__ out) {
    const int lane = threadIdx.x & 63;
    const int tp   = threadIdx.x >> 6;               // 0..7 m-partition
    const int b    = blockIdx.x >> 6;
    const int n0   = (blockIdx.x & 63) * 64;
    const int g16  = lane >> 4, c16 = lane & 15;
    const long bb  = (long)b * 4096;

    f16x4 fbv[4];
    #pragma unroll
    for (int j = 0; j < 4; ++j)
        fbv[j] = *(const f16x4*)(F + (bb + n0 + 16 * j + c16) * 16 + g16 * 4);

    // epilogue assignment: wave tp -> n-tile jo, col-tiles 4*th .. 4*th+3
    const int jo = tp >> 1, th = tp & 1;
    const float gm = gamma[0];
    f16x4 wvf[4];
    #pragma unroll
    for (int t = 0; t < 4; ++t) {
        const int c0 = (4 * th + t) * 16;
        wvf[t] = pk4(wv[(g16 * 4 + 0) * 128 + c0 + c16] * gm,
                     wv[(g16 * 4 + 1) * 128 + c0 + c16] * gm,
                     wv[(g16 * 4 + 2) * 128 + c0 + c16] * gm,
                     wv[(g16 * 4 + 3) * 128 + c0 + c16] * gm);
    }

    const f16* Gp = G + (bb) * 16;
    const f16* Hp = Hs + (long)c16 * 32768 + bb;
    const float* Np = nM2 + bb;
    int m0 = tp * 512;

    f32x4 yT[4] = {{0,0,0,0},{0,0,0,0},{0,0,0,0},{0,0,0,0}};
    f16x4 ga = *(const f16x4*)(Gp + (m0 + c16) * 16 + g16 * 4);
    f16x4 ha = *(const f16x4*)(Hp + m0 + g16 * 4);
    f32x4 nm = *(const f32x4*)(Np + m0 + g16 * 4);
    for (int t = 0; t < 32; ++t) {
        const int m1 = m0 + 16;          // buffers padded: last over-read safe
        f16x4 gan = *(const f16x4*)(Gp + (m1 + c16) * 16 + g16 * 4);
        f16x4 han = *(const f16x4*)(Hp + m1 + g16 * 4);
        f32x4 nmn = *(const f32x4*)(Np + m1 + g16 * 4);
        #pragma unroll
        for (int j = 0; j < 4; ++j) {
            f32x4 zero = {0,0,0,0};
            f32x4 s = MFMA(ga, fbv[j], zero);
            f16x4 pb = pk4(fexp2(fmaf(s[0], LOG2E, nm[0])),
                           fexp2(fmaf(s[1], LOG2E, nm[1])),
                           fexp2(fmaf(s[2], LOG2E, nm[2])),
                           fexp2(fmaf(s[3], LOG2E, nm[3])));
            yT[j] = MFMA(ha, pb, yT[j]);
        }
        ga = gan; ha = han; nm = nmn; m0 = m1;
    }

    // cross-wave reduce: 8 m-partials per n-tile
    __shared__ float red[8][4][64][5];        // 40 KB, stride-5: conflict-free
    #pragma unroll
    for (int j = 0; j < 4; ++j)
        #pragma unroll
        for (int i = 0; i < 4; ++i) red[tp][j][lane][i] = yT[j][i];
    __syncthreads();

    f32x4 ys = {0,0,0,0};
    #pragma unroll
    for (int p = 0; p < 8; ++p)
        #pragma unroll
        for (int i = 0; i < 4; ++i) ys[i] += red[p][jo][lane][i];
    const f16x4 ya = pk4(ys[0], ys[1], ys[2], ys[3]);   // Y A-frag, n-tile jo

    #pragma unroll
    for (int t = 0; t < 4; ++t) {
        const int c0 = (4 * th + t) * 16;
        f32x4 zero = {0,0,0,0};
        f32x4 o = MFMA(ya, wvf[t], zero);
        #pragma unroll
        for (int i = 0; i < 4; ++i) {
            const long idx = (bb + n0 + 16 * jo + 4 * g16 + i) * 128 + c0 + c16;
            out[idx] = o[i] + xin[idx];
        }
    }
}

// ---------------------------------------------------------------------------
extern "C" void kernel_launch(void* const* d_in, const int* in_sizes, int n_in,
                              void* d_out, int out_size, void* d_ws, size_t ws_size,
                              hipStream_t stream) {
    const float* x     = (const float*)d_in[0];
    const float* wf    = (const float*)d_in[1];
    const float* wg    = (const float*)d_in[2];
    const float* wh    = (const float*)d_in[3];
    const float* wv    = (const float*)d_in[4];
    const float* gamma = (const float*)d_in[5];
    float* out = (float*)d_out;

    char* p = (char*)d_ws;
    const long BN  = 8L * 4096;                // 32768 rows
    const long PAD = 4096;                     // inter-buffer slack: prefetch over-reads
    f16*   F   = (f16*)p;    p += BN * 16 * sizeof(f16)   + PAD;
    f16*   G   = (f16*)p;    p += BN * 16 * sizeof(f16)   + PAD;
    float* Ht  = (float*)p;  p += 16 * BN * sizeof(float) + PAD;
    f16*   Hs  = (f16*)p;    p += 16 * BN * sizeof(f16)   + PAD;
    float* nM2 = (float*)p;  p += BN * sizeof(float)      + PAD;
    float* RZ  = (float*)p;  p += BN * sizeof(float)      + PAD;

    k_proj<<<512, 256, 0, stream>>>(x, wf, wg, wh, F, G, Ht);
    k_cs  <<<512, 512, 0, stream>>>(F, G, nM2, RZ);
    k_hs  <<<512, 256, 0, stream>>>(Ht, RZ, Hs);
    k_pv  <<<512, 512, 0, stream>>>(F, G, Hs, nM2, wv, x, gamma, out);
}

// Round 8
// 68.965 us; speedup vs baseline: 7.1227x; 1.0449x over previous
//
#include <hip/hip_runtime.h>

typedef _Float16 f16;
typedef _Float16 f16x4 __attribute__((ext_vector_type(4)));
typedef _Float16 n16x2 __attribute__((ext_vector_type(2)));
typedef float    f32x4 __attribute__((ext_vector_type(4)));

#define LOG2E 1.44269504088896340736f
#define OFF25 36.0673760222824936f   /* 25 * log2(e) */

__device__ __forceinline__ f32x4 MFMA(f16x4 a, f16x4 b, f32x4 c) {
#if defined(__HIP_DEVICE_COMPILE__)
    return __builtin_amdgcn_mfma_f32_16x16x16f16(a, b, c, 0, 0, 0);
#else
    return c;   // host parse stub — never executed
#endif
}

__device__ __forceinline__ float fexp2(float x) {
#if defined(__HIP_DEVICE_COMPILE__)
    return __builtin_amdgcn_exp2f(x);
#else
    return exp2f(x);
#endif
}

__device__ __forceinline__ f16x4 pk4(float a, float b, float c, float d) {
#if defined(__HIP_DEVICE_COMPILE__)
    n16x2 lo = __builtin_bit_cast(n16x2, __builtin_amdgcn_cvt_pkrtz(a, b));
    n16x2 hi = __builtin_bit_cast(n16x2, __builtin_amdgcn_cvt_pkrtz(c, d));
    f16x4 r; r[0] = lo[0]; r[1] = lo[1]; r[2] = hi[0]; r[3] = hi[1];
    return r;
#else
    f16x4 r; r[0] = (f16)a; r[1] = (f16)b; r[2] = (f16)c; r[3] = (f16)d;
    return r;
#endif
}

// ---------------------------------------------------------------------------
// K1: projections, K-split.  Block = 2 row-tiles x 2 K-halves (4 waves).
// Each wave: 12 MFMAs over its 64-channel half; halves combined via LDS
// (stride-13 f32 -> conflict-free).  F,G row-major f16; H transposed f32.
// ---------------------------------------------------------------------------
__global__ __launch_bounds__(256) void k_proj(const float* __restrict__ x,
        const float* __restrict__ wf, const float* __restrict__ wg,
        const float* __restrict__ wh, f16* __restrict__ F,
        f16* __restrict__ G, float* __restrict__ Ht) {
    const int lane = threadIdx.x & 63;
    const int wid  = threadIdx.x >> 6;
    const int tile = wid >> 1;           // 0..1 row-tile
    const int kh   = wid & 1;            // 0..1 K-half
    const int g16  = lane >> 4;          // 0..3
    const int c16  = lane & 15;          // 0..15
    const long r0  = ((long)blockIdx.x * 2 + tile) * 16;

    f16x4 bw[3][4];
    const float* Ws[3] = { wf, wg, wh };
    #pragma unroll
    for (int w = 0; w < 3; ++w)
        #pragma unroll
        for (int kk = 0; kk < 4; ++kk) {
            const int kb = (kh * 4 + kk) * 16 + g16 * 4;
            bw[w][kk] = pk4(Ws[w][(kb + 0) * 16 + c16], Ws[w][(kb + 1) * 16 + c16],
                            Ws[w][(kb + 2) * 16 + c16], Ws[w][(kb + 3) * 16 + c16]);
        }

    f32x4 af = {0,0,0,0}, ag = {0,0,0,0}, ah = {0,0,0,0};
    const float* xr = x + (r0 + c16) * 128;
    #pragma unroll
    for (int kk = 0; kk < 4; ++kk) {
        float4 xa = *(const float4*)(xr + (kh * 4 + kk) * 16 + g16 * 4);
        f16x4 a = pk4(xa.x, xa.y, xa.z, xa.w);
        af = MFMA(a, bw[0][kk], af);
        ag = MFMA(a, bw[1][kk], ag);
        ah = MFMA(a, bw[2][kk], ah);
    }

    __shared__ float red[2][64][13];     // stride 13: conflict-free
    if (kh == 1) {
        #pragma unroll
        for (int i = 0; i < 4; ++i) {
            red[tile][lane][i]     = af[i];
            red[tile][lane][4 + i] = ag[i];
            red[tile][lane][8 + i] = ah[i];
        }
    }
    __syncthreads();
    if (kh == 0) {
        #pragma unroll
        for (int i = 0; i < 4; ++i) {
            af[i] += red[tile][lane][i];
            ag[i] += red[tile][lane][4 + i];
            ah[i] += red[tile][lane][8 + i];
        }
        #pragma unroll
        for (int i = 0; i < 4; ++i) {
            const long row = r0 + g16 * 4 + i;
            F[row * 16 + c16] = (f16)af[i];
            G[row * 16 + c16] = (f16)ag[i];
        }
        float4 hv = make_float4(ah[0], ah[1], ah[2], ah[3]);
        *(float4*)(Ht + (long)c16 * 32768 + r0 + g16 * 4) = hv;
    }
}

// ---------------------------------------------------------------------------
// K2: column stats + fused Hs scaling.  Block = 64 m (ga[4] tiles/wave),
// 8 waves = 8 n-eighths, depth-2 register prefetch of the F fragment.
// Epilogue: block owns Z for its 64 columns -> writes nM2 and
// Hs[d][m] = f16(Ht[d][m] * RZ[m]) directly.
// ---------------------------------------------------------------------------
__global__ __launch_bounds__(512) void k_cs(const f16* __restrict__ F,
        const f16* __restrict__ G, const float* __restrict__ Ht,
        float* __restrict__ nM2, f16* __restrict__ Hs) {
    const int lane = threadIdx.x & 63;
    const int tp   = threadIdx.x >> 6;               // 0..7 n-partition
    const int b    = blockIdx.x >> 6;
    const int mb   = (blockIdx.x & 63) * 64;
    const int g16  = lane >> 4, c16 = lane & 15;
    const long bb  = (long)b * 4096;

    f16x4 ga[4];
    #pragma unroll
    for (int j = 0; j < 4; ++j)
        ga[j] = *(const f16x4*)(G + (bb + mb + 16 * j + c16) * 16 + g16 * 4);

    const f16* Fb = F + (bb + tp * 512) * 16;
    float qm[4][4], zs[4][4];
    #pragma unroll
    for (int j = 0; j < 4; ++j)
        #pragma unroll
        for (int i = 0; i < 4; ++i) { qm[j][i] = -1e30f; zs[j][i] = 0.f; }

    f16x4 fb0 = *(const f16x4*)(Fb + (c16) * 16 + g16 * 4);
    f16x4 fb1 = *(const f16x4*)(Fb + (16 + c16) * 16 + g16 * 4);
    for (int t = 0; t < 32; ++t) {
        // depth-2 prefetch (buffers padded: safe over-read)
        f16x4 fbn = *(const f16x4*)(Fb + ((t + 2) * 16 + c16) * 16 + g16 * 4);
        #pragma unroll
        for (int j = 0; j < 4; ++j) {
            f32x4 zero = {0,0,0,0};
            f32x4 s = MFMA(ga[j], fb0, zero);
            #pragma unroll
            for (int i = 0; i < 4; ++i) {
                const float q = fmaf(s[i], LOG2E, -OFF25);
                zs[j][i] += fexp2(q);
                qm[j][i] = fmaxf(qm[j][i], q);
            }
        }
        fb0 = fb1; fb1 = fbn;
    }
    #pragma unroll
    for (int d = 8; d >= 1; d >>= 1)
        #pragma unroll
        for (int j = 0; j < 4; ++j)
            #pragma unroll
            for (int i = 0; i < 4; ++i) {
                qm[j][i] = fmaxf(qm[j][i], __shfl_xor(qm[j][i], d));
                zs[j][i] += __shfl_xor(zs[j][i], d);
            }

    __shared__ float lq[8][64], lz[8][64], lrz[64];
    if (c16 == 0) {
        #pragma unroll
        for (int j = 0; j < 4; ++j)
            #pragma unroll
            for (int i = 0; i < 4; ++i) {
                const int ml = 16 * j + 4 * g16 + i;
                lq[tp][ml] = qm[j][i];
                lz[tp][ml] = zs[j][i];
            }
    }
    __syncthreads();
    if (threadIdx.x < 64) {
        const int ml = threadIdx.x;
        float q = lq[0][ml], z = 0.f;
        #pragma unroll
        for (int p = 1; p < 8; ++p) q = fmaxf(q, lq[p][ml]);
        #pragma unroll
        for (int p = 0; p < 8; ++p) z += lz[p][ml];
        nM2[bb + mb + ml] = -q - OFF25;
        lrz[ml] = fexp2(q) / z;
    }
    __syncthreads();
    // fused Hs epilogue: wave tp handles d = 2*tp, 2*tp+1 (64-wide coalesced)
    #pragma unroll
    for (int r = 0; r < 2; ++r) {
        const int d = tp * 2 + r;
        const long a = (long)d * 32768 + bb + mb + lane;
        Hs[a] = (f16)(Ht[a] * lrz[lane]);
    }
}

// ---------------------------------------------------------------------------
// K3: PV + fused output projection.  Block = 64 n-rows (fbv[4] tiles), 8
// waves = 8 m-eighths (512 m, 32 iters), depth-2 register prefetch of
// {ga, ha, nm}.  8-partial LDS reduce; epilogue split across all 8 waves.
// ---------------------------------------------------------------------------
__global__ __launch_bounds__(512) void k_pv(const f16* __restrict__ F,
        const f16* __restrict__ G, const f16* __restrict__ Hs,
        const float* __restrict__ nM2, const float* __restrict__ wv,
        const float* __restrict__ xin, const float* __restrict__ gamma,
        float* __restrict__ out) {
    const int lane = threadIdx.x & 63;
    const int tp   = threadIdx.x >> 6;               // 0..7 m-partition
    const int b    = blockIdx.x >> 6;
    const int n0   = (blockIdx.x & 63) * 64;
    const int g16  = lane >> 4, c16 = lane & 15;
    const long bb  = (long)b * 4096;

    f16x4 fbv[4];
    #pragma unroll
    for (int j = 0; j < 4; ++j)
        fbv[j] = *(const f16x4*)(F + (bb + n0 + 16 * j + c16) * 16 + g16 * 4);

    // epilogue assignment: wave tp -> n-tile jo, col-tiles 4*th .. 4*th+3
    const int jo = tp >> 1, th = tp & 1;
    const float gm = gamma[0];
    f16x4 wvf[4];
    #pragma unroll
    for (int t = 0; t < 4; ++t) {
        const int c0 = (4 * th + t) * 16;
        wvf[t] = pk4(wv[(g16 * 4 + 0) * 128 + c0 + c16] * gm,
                     wv[(g16 * 4 + 1) * 128 + c0 + c16] * gm,
                     wv[(g16 * 4 + 2) * 128 + c0 + c16] * gm,
                     wv[(g16 * 4 + 3) * 128 + c0 + c16] * gm);
    }

    const f16* Gp = G + (bb) * 16;
    const f16* Hp = Hs + (long)c16 * 32768 + bb;
    const float* Np = nM2 + bb;
    const int mbase = tp * 512;

    f32x4 yT[4] = {{0,0,0,0},{0,0,0,0},{0,0,0,0},{0,0,0,0}};
    f16x4 ga0 = *(const f16x4*)(Gp + (mbase + c16) * 16 + g16 * 4);
    f16x4 ha0 = *(const f16x4*)(Hp + mbase + g16 * 4);
    f32x4 nm0 = *(const f32x4*)(Np + mbase + g16 * 4);
    f16x4 ga1 = *(const f16x4*)(Gp + (mbase + 16 + c16) * 16 + g16 * 4);
    f16x4 ha1 = *(const f16x4*)(Hp + mbase + 16 + g16 * 4);
    f32x4 nm1 = *(const f32x4*)(Np + mbase + 16 + g16 * 4);
    for (int t = 0; t < 32; ++t) {
        const int m2 = mbase + t * 16 + 32;   // depth-2; padded: over-read safe
        f16x4 gan = *(const f16x4*)(Gp + (m2 + c16) * 16 + g16 * 4);
        f16x4 han = *(const f16x4*)(Hp + m2 + g16 * 4);
        f32x4 nmn = *(const f32x4*)(Np + m2 + g16 * 4);
        #pragma unroll
        for (int j = 0; j < 4; ++j) {
            f32x4 zero = {0,0,0,0};
            f32x4 s = MFMA(ga0, fbv[j], zero);
            f16x4 pb = pk4(fexp2(fmaf(s[0], LOG2E, nm0[0])),
                           fexp2(fmaf(s[1], LOG2E, nm0[1])),
                           fexp2(fmaf(s[2], LOG2E, nm0[2])),
                           fexp2(fmaf(s[3], LOG2E, nm0[3])));
            yT[j] = MFMA(ha0, pb, yT[j]);
        }
        ga0 = ga1; ha0 = ha1; nm0 = nm1;
        ga1 = gan; ha1 = han; nm1 = nmn;
    }

    // cross-wave reduce: 8 m-partials per n-tile
    __shared__ float red[8][4][64][5];        // 40 KB, stride-5: conflict-free
    #pragma unroll
    for (int j = 0; j < 4; ++j)
        #pragma unroll
        for (int i = 0; i < 4; ++i) red[tp][j][lane][i] = yT[j][i];
    __syncthreads();

    f32x4 ys = {0,0,0,0};
    #pragma unroll
    for (int p = 0; p < 8; ++p)
        #pragma unroll
        for (int i = 0; i < 4; ++i) ys[i] += red[p][jo][lane][i];
    const f16x4 ya = pk4(ys[0], ys[1], ys[2], ys[3]);   // Y A-frag, n-tile jo

    #pragma unroll
    for (int t = 0; t < 4; ++t) {
        const int c0 = (4 * th + t) * 16;
        f32x4 zero = {0,0,0,0};
        f32x4 o = MFMA(ya, wvf[t], zero);
        #pragma unroll
        for (int i = 0; i < 4; ++i) {
            const long idx = (bb + n0 + 16 * jo + 4 * g16 + i) * 128 + c0 + c16;
            out[idx] = o[i] + xin[idx];
        }
    }
}

// ---------------------------------------------------------------------------
extern "C" void kernel_launch(void* const* d_in, const int* in_sizes, int n_in,
                              void* d_out, int out_size, void* d_ws, size_t ws_size,
                              hipStream_t stream) {
    const float* x     = (const float*)d_in[0];
    const float* wf    = (const float*)d_in[1];
    const float* wg    = (const float*)d_in[2];
    const float* wh    = (const float*)d_in[3];
    const float* wv    = (const float*)d_in[4];
    const float* gamma = (const float*)d_in[5];
    float* out = (float*)d_out;

    char* p = (char*)d_ws;
    const long BN  = 8L * 4096;                // 32768 rows
    const long PAD = 8192;                     // inter-buffer slack: prefetch over-reads
    f16*   F   = (f16*)p;    p += BN * 16 * sizeof(f16)   + PAD;
    f16*   G   = (f16*)p;    p += BN * 16 * sizeof(f16)   + PAD;
    float* Ht  = (float*)p;  p += 16 * BN * sizeof(float) + PAD;
    f16*   Hs  = (f16*)p;    p += 16 * BN * sizeof(f16)   + PAD;
    float* nM2 = (float*)p;  p += BN * sizeof(float)      + PAD;

    k_proj<<<1024, 256, 0, stream>>>(x, wf, wg, wh, F, G, Ht);
    k_cs  <<<512,  512, 0, stream>>>(F, G, Ht, nM2, Hs);
    k_pv  <<<512,  512, 0, stream>>>(F, G, Hs, nM2, wv, x, gamma, out);
}